// Round 6
// baseline (130.661 us; speedup 1.0000x reference)
//
#include <hip/hip_runtime.h>

// CompoundClassifier, round 6: r5 + W1/W2 pre-converted to f16 (separate tiny
// kernel) so pq_gemm's B-fragments are vector b128 loads instead of a 64-deep
// scalar f32 load storm (512-B stride, ~1.9M segments, serialized on vmcnt).
// Edge kernel held structurally identical to r5 for clean attribution.
//   P = x_ing @ W1[:128]        (20000x128 f16)
//   Q = x_cmp @ W1[128:] + b1   (10000x128 f16)
//   out[e] = sigmoid( relu(P[s]+Q[d]) . W2 + b2 )

#define H  128
#define NI 20000
#define NC 10000
#define NE 1000000

typedef _Float16 half2v __attribute__((ext_vector_type(2)));
typedef _Float16 half8  __attribute__((ext_vector_type(8)));
typedef float    floatx4 __attribute__((ext_vector_type(4)));

// ws layout in halfs (~7.75 MB)
#define P_OFF   0
#define Q_OFF   (NI * H)                 // 2,560,000
#define W1T_OFF ((NI + NC) * H)          // 3,840,000  : W1 transposed [n][256]
#define W2H_OFF (W1T_OFF + 256 * H)     // 3,872,768  : W2 as f16 [128]

#define PB (NI / 16)   // 1250
#define QB (NC / 16)   // 625

// ---- one-shot weight conversion: W1 -> f16 transposed [n][k], W2 -> f16 ----
__launch_bounds__(256)
__global__ void cvt_w(const float* __restrict__ W1,   // [256][128] row-major
                      const float* __restrict__ W2,   // [128]
                      _Float16* __restrict__ ws) {
    const int b = blockIdx.x;
    if (b < 128) {
        const int i = b * 256 + threadIdx.x;          // over 128*256
        const int n = i >> 8, k = i & 255;
        ws[W1T_OFF + i] = (_Float16)W1[k * H + n];
    } else if (threadIdx.x < H) {
        ws[W2H_OFF + threadIdx.x] = (_Float16)W2[threadIdx.x];
    }
}

// ---- P/Q precompute: 16x16x32 f16 MFMA (fragment layouts verified r1/r3) ----
__launch_bounds__(256)
__global__ void pq_gemm(const float* __restrict__ xin,
                        const float* __restrict__ xcmp,
                        const float* __restrict__ b1,
                        _Float16* __restrict__ ws) {
    const int b    = blockIdx.x;
    const bool isQ = (b >= PB);
    const int  rb  = (isQ ? b - PB : b) * 16;
    const float* X = isQ ? xcmp : xin;
    const int kofs = isQ ? H : 0;
    _Float16* OUT  = ws + (isQ ? Q_OFF : P_OFF);
    const _Float16* w1t = ws + W1T_OFF;

    const int lane = threadIdx.x & 63;
    const int w    = threadIdx.x >> 6;
    const int quad = lane >> 4;
    const int m    = lane & 15;

    // B-fragments: clean b128 loads from L2-hot f16 W1T (coalesced across m)
    half8 bf[2][4];
    float b1v[2];
#pragma unroll
    for (int nt = 0; nt < 2; ++nt) {
        const int n = w * 32 + nt * 16 + m;
        const _Float16* wp = w1t + n * 256 + kofs + quad * 8;
#pragma unroll
        for (int ks = 0; ks < 4; ++ks)
            bf[nt][ks] = *(const half8*)(wp + ks * 32);
        b1v[nt] = isQ ? b1[n] : 0.0f;
    }

    // A-fragments: row rb+m, contiguous 8 floats -> half8 (coalesced f32 loads)
    half8 af[4];
    const float* xr = X + (long)(rb + m) * H + quad * 8;
#pragma unroll
    for (int ks = 0; ks < 4; ++ks) {
        float4 a = *(const float4*)(xr + ks * 32);
        float4 c = *(const float4*)(xr + ks * 32 + 4);
        half8 v = { (_Float16)a.x, (_Float16)a.y, (_Float16)a.z, (_Float16)a.w,
                    (_Float16)c.x, (_Float16)c.y, (_Float16)c.z, (_Float16)c.w };
        af[ks] = v;
    }

    floatx4 acc[2] = { (floatx4)0.0f, (floatx4)0.0f };
#pragma unroll
    for (int ks = 0; ks < 4; ++ks)
#pragma unroll
        for (int nt = 0; nt < 2; ++nt)
            acc[nt] = __builtin_amdgcn_mfma_f32_16x16x32_f16(af[ks], bf[nt][ks], acc[nt], 0, 0, 0);

    // C/D: col = lane&15 within n-tile, row = quad*4 + r
#pragma unroll
    for (int nt = 0; nt < 2; ++nt) {
        const int col = w * 32 + nt * 16 + m;
#pragma unroll
        for (int r = 0; r < 4; ++r)
            OUT[(rb + quad * 4 + r) * H + col] = (_Float16)(acc[nt][r] + b1v[nt]);
    }
}

// ---- edge kernel (structurally r5): 8 threads/edge, packed f16 math ----
#define EPB   160            // edges per block = 5 passes x 32
#define EGRID (NE / EPB)     // 6250 (exact)

__launch_bounds__(256)
__global__ void edge_mlp(const _Float16* __restrict__ ws,
                         const int* __restrict__ src_idx,
                         const int* __restrict__ dst_idx,
                         const float* __restrict__ b2p,
                         float* __restrict__ out) {
    const int tid  = threadIdx.x;
    const int c    = tid & 7;
    const int slot = tid >> 3;      // 0..31: edge within pass

    // W2 sixteenth as 8 packed half2 (2 b128 loads, amortized over 5 edges)
    const _Float16* w2c = ws + W2H_OFF + c * 16;
    half8 wlo = *(const half8*)(w2c);
    half8 whi = *(const half8*)(w2c + 8);
    const float b2v = b2p[0];

    int e  = blockIdx.x * EPB + slot;
    int si = src_idx[e];
    int di = dst_idx[e];

#pragma unroll 1
    for (int it = 0; it < 5; ++it) {
        const _Float16* pr = ws + P_OFF + (long)si * H + c * 16;
        const _Float16* qr = ws + Q_OFF + (long)di * H + c * 16;
        half8 p0 = *(const half8*)(pr);
        half8 p1 = *(const half8*)(pr + 8);
        half8 q0 = *(const half8*)(qr);
        half8 q1 = *(const half8*)(qr + 8);

        // prefetch next pass's indices while the row gathers are in flight
        int si2 = si, di2 = di;
        if (it < 4) { si2 = src_idx[e + 32]; di2 = dst_idx[e + 32]; }

        half8 h0 = p0 + q0;            // v_pk_add_f16 x4
        half8 h1 = p1 + q1;
        const half8 z = {};
#if __has_builtin(__builtin_elementwise_max)
        h0 = __builtin_elementwise_max(h0, z);   // v_pk_max_f16 x4
        h1 = __builtin_elementwise_max(h1, z);
#else
#pragma unroll
        for (int j = 0; j < 8; ++j) {
            h0[j] = h0[j] > (_Float16)0 ? h0[j] : (_Float16)0;
            h1[j] = h1[j] > (_Float16)0 ? h1[j] : (_Float16)0;
        }
#endif

        float acc = 0.0f;
#pragma unroll
        for (int j = 0; j < 4; ++j) {
            half2v a = { h0[2 * j], h0[2 * j + 1] };
            half2v wv = { wlo[2 * j], wlo[2 * j + 1] };
#if __has_builtin(__builtin_amdgcn_fdot2)
            acc = __builtin_amdgcn_fdot2(a, wv, acc, false);   // v_dot2_f32_f16
#else
            acc += (float)a[0] * (float)wv[0] + (float)a[1] * (float)wv[1];
#endif
        }
#pragma unroll
        for (int j = 0; j < 4; ++j) {
            half2v a = { h1[2 * j], h1[2 * j + 1] };
            half2v wv = { whi[2 * j], whi[2 * j + 1] };
#if __has_builtin(__builtin_amdgcn_fdot2)
            acc = __builtin_amdgcn_fdot2(a, wv, acc, false);
#else
            acc += (float)a[0] * (float)wv[0] + (float)a[1] * (float)wv[1];
#endif
        }

        // reduce over the 8-lane edge group
        acc += __shfl_xor(acc, 1);
        acc += __shfl_xor(acc, 2);
        acc += __shfl_xor(acc, 4);

        if (c == 0)
            out[e] = 1.0f / (1.0f + expf(-(acc + b2v)));

        e += 32; si = si2; di = di2;
    }
}

extern "C" void kernel_launch(void* const* d_in, const int* in_sizes, int n_in,
                              void* d_out, int out_size, void* d_ws, size_t ws_size,
                              hipStream_t stream) {
    const float* xin  = (const float*)d_in[0];
    const float* xcmp = (const float*)d_in[1];
    const int*   eidx = (const int*)d_in[2];    // [2,E]: first E src, next E dst
    const float* W1   = (const float*)d_in[3];
    const float* b1   = (const float*)d_in[4];
    const float* W2   = (const float*)d_in[5];
    const float* b2   = (const float*)d_in[6];
    float* out = (float*)d_out;
    _Float16* ws = (_Float16*)d_ws;             // ~7.75 MB used

    hipLaunchKernelGGL(cvt_w, dim3(129), dim3(256), 0, stream, W1, W2, ws);
    hipLaunchKernelGGL(pq_gemm, dim3(PB + QB), dim3(256), 0, stream,
                       xin, xcmp, b1, ws);
    hipLaunchKernelGGL(edge_mlp, dim3(EGRID), dim3(256), 0, stream,
                       ws, eidx, eidx + NE, b2, out);
}

// Round 7
// 114.908 us; speedup vs baseline: 1.1371x; 1.1371x over previous
//
#include <hip/hip_runtime.h>

// CompoundClassifier, round 7: fp8(e4m3) P/Q tables.
//   P = x_ing @ W1[:128], Q = x_cmp @ W1[128:] + b1  -> stored as fp8 (1 B/el)
//   out[e] = sigmoid( relu(P[s]+Q[d]) . W2 + b2 )
// r4/r5 evidence: edge kernel is gather-path bound (int8-heavy and f16-lean
// inner math both land ~45-50us). fp8 tables: 3.84 MB (per-XCD-L2-resident),
// 1 line/row, HW pk decode (2 el/inst) -> granules/edge ~9 -> ~4.2 and no
// bfe storm. Encode in pq epilogue via v_cvt_pk_fp8_f32 (no scale pass).

#define H  128
#define NI 20000
#define NC 10000
#define NE 1000000

typedef _Float16 half8   __attribute__((ext_vector_type(8)));
typedef float    floatx2 __attribute__((ext_vector_type(2)));
typedef float    floatx4 __attribute__((ext_vector_type(4)));

// ws byte layout
#define P8_OFF    0
#define Q8_OFF    (NI * H)                    // 2,560,000
#define WFRAG_B   ((NI + NC) * H)             // 3,840,000 (16B aligned)
// WFRAG: W1 as f16 in MFMA B-fragment order, 64 KB:
//   flat = ((isQ*8 + w*2+nt)*4 + ks)*512 + lane*8 + j
//   holds W1[k][n], k = isQ*128 + ks*32 + (lane>>4)*8 + j,
//                   n = (w)*32 + nt*16 + (lane&15)         (w*2+nt = ntw)

#define PB (NI / 16)   // 1250
#define QB (NC / 16)   // 625

// ---------- fp8 e4m3 helpers (HW path on gfx950; SW fallback for safety) ----
#if __has_builtin(__builtin_amdgcn_cvt_pk_f32_fp8) && __has_builtin(__builtin_amdgcn_cvt_pk_fp8_f32)
#define HW_FP8 1
#else
#define HW_FP8 0
__device__ inline unsigned char enc_e4m3(float x) {
    unsigned s = x < 0.0f ? 0x80u : 0u;
    float a = fminf(fabsf(x), 448.0f);
    if (a < 0.0009765625f) return (unsigned char)s;       // < 2^-10 -> 0
    int e; float m = frexpf(a, &e);                       // a = m*2^e, m in [0.5,1)
    int E = e + 6;                                        // biased exp
    if (E <= 0) {                                         // subnormal: f*2^-9
        int f = (int)rintf(a * 512.0f);
        if (f > 7) return (unsigned char)(s | 0x08);
        return (unsigned char)(s | f);
    }
    int f = (int)rintf((m * 2.0f - 1.0f) * 8.0f);
    if (f == 8) { f = 0; ++E; }
    if (E > 15 || (E == 15 && f > 6)) { E = 15; f = 6; }  // clamp to 448
    return (unsigned char)(s | (E << 3) | f);
}
__device__ inline float dec_e4m3(unsigned char b) {
    int E = (b >> 3) & 15, f = b & 7;
    float v = (E == 0) ? (float)f * 0.001953125f          // f * 2^-9
                       : (float)(8 + f) * exp2f((float)(E - 10));
    return (b & 0x80) ? -v : v;
}
#endif

// ---------- one-shot: W1 -> f16 fragment-ordered table ----------
__launch_bounds__(256)
__global__ void cvt_w(const float* __restrict__ W1,   // [256][128] row-major
                      unsigned char* __restrict__ wsb) {
    const int flat = blockIdx.x * 256 + threadIdx.x;   // over 32768
    const int j    = flat & 7;
    const int lane = (flat >> 3) & 63;
    const int ks   = (flat >> 9) & 3;
    const int ntw  = (flat >> 11) & 7;
    const int isQ  = (flat >> 14) & 1;
    const int n = (ntw >> 1) * 32 + (ntw & 1) * 16 + (lane & 15);
    const int k = isQ * 128 + ks * 32 + (lane >> 4) * 8 + j;
    ((_Float16*)(wsb + WFRAG_B))[flat] = (_Float16)W1[k * H + n];
}

// ---------- P/Q precompute: 16x16x32 f16 MFMA, fp8 epilogue ----------
__launch_bounds__(256)
__global__ void pq_gemm(const float* __restrict__ xin,
                        const float* __restrict__ xcmp,
                        const float* __restrict__ b1,
                        unsigned char* __restrict__ wsb) {
    const int b    = blockIdx.x;
    const bool isQ = (b >= PB);
    const int  rb  = (isQ ? b - PB : b) * 16;
    const float* X = isQ ? xcmp : xin;
    unsigned char* OUT8 = wsb + (isQ ? Q8_OFF : P8_OFF);
    const _Float16* wfrag = (const _Float16*)(wsb + WFRAG_B);

    const int lane = threadIdx.x & 63;
    const int w    = threadIdx.x >> 6;
    const int quad = lane >> 4;
    const int m    = lane & 15;

    // B-fragments: lane-contiguous b128 from the fragment-ordered table
    half8 bf[2][4];
    float b1v[2];
#pragma unroll
    for (int nt = 0; nt < 2; ++nt) {
        const int ntw = w * 2 + nt;
#pragma unroll
        for (int ks = 0; ks < 4; ++ks)
            bf[nt][ks] = *(const half8*)(wfrag + (((isQ ? 8 : 0) + ntw) * 4 + ks) * 512 + lane * 8);
        const int n = w * 32 + nt * 16 + m;
        b1v[nt] = isQ ? b1[n] : 0.0f;
    }

    // A-fragments: row rb+m, contiguous 8 floats -> half8
    half8 af[4];
    const float* xr = X + (long)(rb + m) * H + quad * 8;
#pragma unroll
    for (int ks = 0; ks < 4; ++ks) {
        float4 a = *(const float4*)(xr + ks * 32);
        float4 c = *(const float4*)(xr + ks * 32 + 4);
        half8 v = { (_Float16)a.x, (_Float16)a.y, (_Float16)a.z, (_Float16)a.w,
                    (_Float16)c.x, (_Float16)c.y, (_Float16)c.z, (_Float16)c.w };
        af[ks] = v;
    }

    floatx4 acc[2] = { (floatx4)0.0f, (floatx4)0.0f };
#pragma unroll
    for (int ks = 0; ks < 4; ++ks)
#pragma unroll
        for (int nt = 0; nt < 2; ++nt)
            acc[nt] = __builtin_amdgcn_mfma_f32_16x16x32_f16(af[ks], bf[nt][ks], acc[nt], 0, 0, 0);

    // epilogue: +b1, encode fp8, byte stores (rows contiguous in m -> coalesced)
    // C/D: col = lane&15 within n-tile, row = quad*4 + r
#pragma unroll
    for (int nt = 0; nt < 2; ++nt) {
        const int col = w * 32 + nt * 16 + m;
#pragma unroll
        for (int r = 0; r < 4; ++r) {
            const float v = acc[nt][r] + b1v[nt];
#if HW_FP8
            const unsigned u = (unsigned)__builtin_amdgcn_cvt_pk_fp8_f32(v, v, 0, false);
            OUT8[(rb + quad * 4 + r) * H + col] = (unsigned char)(u & 0xff);
#else
            OUT8[(rb + quad * 4 + r) * H + col] = enc_e4m3(v);
#endif
        }
    }
}

// ---------- edge kernel: 8 lanes/edge, fp8 rows, HW pk decode ----------
#define EGRID 2048

__launch_bounds__(256)
__global__ void edge_mlp(const unsigned char* __restrict__ wsb,
                         const int* __restrict__ src_idx,
                         const int* __restrict__ dst_idx,
                         const float* __restrict__ W2,
                         const float* __restrict__ b2p,
                         float* __restrict__ out) {
    const int tid  = threadIdx.x;
    const int c    = tid & 7;       // 16-byte slice of the 128-B row
    const int slot = tid >> 3;      // edge within pass (0..31)

    // W2 slice: 16 floats for cols c*16..c*16+15 (held in regs, reused ~15 passes)
    float4 w2v[4];
#pragma unroll
    for (int i = 0; i < 4; ++i) w2v[i] = *(const float4*)(W2 + c * 16 + i * 4);
    const float b2v = b2p[0];

    const unsigned char* P8 = wsb + P8_OFF;
    const unsigned char* Q8 = wsb + Q8_OFF;

    int e  = blockIdx.x * 32 + slot;
    int si = 0, di = 0;
    if (e < NE) { si = src_idx[e]; di = dst_idx[e]; }

    while (e < NE) {
        const uint4 pd = *(const uint4*)(P8 + si * H + c * 16);
        const uint4 qd = *(const uint4*)(Q8 + di * H + c * 16);

        // prefetch next pass's indices while row loads are in flight
        const int e2 = e + 32 * EGRID;
        int si2 = 0, di2 = 0;
        if (e2 < NE) { si2 = src_idx[e2]; di2 = dst_idx[e2]; }

        float acc = 0.0f;
        const unsigned pw[4] = { pd.x, pd.y, pd.z, pd.w };
        const unsigned qw[4] = { qd.x, qd.y, qd.z, qd.w };
#pragma unroll
        for (int jw = 0; jw < 4; ++jw) {
#if HW_FP8
            floatx2 pl = __builtin_amdgcn_cvt_pk_f32_fp8((int)pw[jw], false);
            floatx2 ph = __builtin_amdgcn_cvt_pk_f32_fp8((int)pw[jw], true);
            floatx2 ql = __builtin_amdgcn_cvt_pk_f32_fp8((int)qw[jw], false);
            floatx2 qh = __builtin_amdgcn_cvt_pk_f32_fp8((int)qw[jw], true);
#else
            floatx2 pl = { dec_e4m3(pw[jw] & 0xff), dec_e4m3((pw[jw] >> 8) & 0xff) };
            floatx2 ph = { dec_e4m3((pw[jw] >> 16) & 0xff), dec_e4m3(pw[jw] >> 24) };
            floatx2 ql = { dec_e4m3(qw[jw] & 0xff), dec_e4m3((qw[jw] >> 8) & 0xff) };
            floatx2 qh = { dec_e4m3((qw[jw] >> 16) & 0xff), dec_e4m3(qw[jw] >> 24) };
#endif
            const float4 wv = w2v[jw];
            acc = fmaf(fmaxf(pl.x + ql.x, 0.0f), wv.x, acc);
            acc = fmaf(fmaxf(pl.y + ql.y, 0.0f), wv.y, acc);
            acc = fmaf(fmaxf(ph.x + qh.x, 0.0f), wv.z, acc);
            acc = fmaf(fmaxf(ph.y + qh.y, 0.0f), wv.w, acc);
        }

        // reduce over the 8-lane edge group
        acc += __shfl_xor(acc, 1);
        acc += __shfl_xor(acc, 2);
        acc += __shfl_xor(acc, 4);

        if (c == 0)
            out[e] = 1.0f / (1.0f + expf(-(acc + b2v)));   // 32 consecutive floats/wave-pass

        e = e2; si = si2; di = di2;
    }
}

extern "C" void kernel_launch(void* const* d_in, const int* in_sizes, int n_in,
                              void* d_out, int out_size, void* d_ws, size_t ws_size,
                              hipStream_t stream) {
    const float* xin  = (const float*)d_in[0];
    const float* xcmp = (const float*)d_in[1];
    const int*   eidx = (const int*)d_in[2];    // [2,E]: first E src, next E dst
    const float* W1   = (const float*)d_in[3];
    const float* b1   = (const float*)d_in[4];
    const float* W2   = (const float*)d_in[5];
    const float* b2   = (const float*)d_in[6];
    float* out = (float*)d_out;
    unsigned char* wsb = (unsigned char*)d_ws;  // ~3.9 MB used

    hipLaunchKernelGGL(cvt_w,   dim3(128),     dim3(256), 0, stream, W1, wsb);
    hipLaunchKernelGGL(pq_gemm, dim3(PB + QB), dim3(256), 0, stream, xin, xcmp, b1, wsb);
    hipLaunchKernelGGL(edge_mlp, dim3(EGRID),  dim3(256), 0, stream,
                       wsb, eidx, eidx + NE, W2, b2, out);
}